// Round 9
// baseline (784.090 us; speedup 1.0000x reference)
//
#include <hip/hip_runtime.h>
#include <math.h>

#define N_NODES 100000
#define N_EDGES 3200000
#define D_FEAT  512
#define D_HID   64
#define N_CLS   40
#define NBKT    391            /* coarse buckets = ceil(N/256), bucket = dst >> 8 */
#define NBLKA   256            /* blocks in passes A/B */
#define EPB     (N_EDGES / NBLKA)   /* 12500 edges per block */

typedef __attribute__((ext_vector_type(8))) short short8;
typedef __attribute__((ext_vector_type(4))) float floatx4;

static __device__ __forceinline__ unsigned short f2bf(float f) {
    unsigned u = __float_as_uint(f);
    unsigned r = (u + 0x7FFFu + ((u >> 16) & 1u)) >> 16;   // RNE
    return (unsigned short)r;
}
static __device__ __forceinline__ float bf2f(unsigned short h) {
    return __uint_as_float(((unsigned)h) << 16);
}
static __device__ __forceinline__ short8 pack_bf16x8(float4 a, float4 b) {
    short8 r;
    r[0] = (short)f2bf(a.x); r[1] = (short)f2bf(a.y);
    r[2] = (short)f2bf(a.z); r[3] = (short)f2bf(a.w);
    r[4] = (short)f2bf(b.x); r[5] = (short)f2bf(b.y);
    r[6] = (short)f2bf(b.z); r[7] = (short)f2bf(b.w);
    return r;
}
static __device__ __forceinline__ int2 nt_load_int2(const int2* p) {
    long long v = __builtin_nontemporal_load((const long long*)p);
    int2 r; r.x = (int)(unsigned)(v & 0xffffffffll); r.y = (int)(v >> 32);
    return r;
}

// ---------------- zero deg ----------------

__global__ __launch_bounds__(256) void k_zero(float* __restrict__ deg) {
    int i = blockIdx.x * 256 + threadIdx.x;
    if (i < N_NODES) deg[i] = 0.f;
}

// ---------------- pass A: coarse histogram + weighted in-degree (global atomics) ----------------

__global__ __launch_bounds__(256) void k_histA(const int* __restrict__ ei,
                                               const float* __restrict__ ew,
                                               int* __restrict__ mat,
                                               float* __restrict__ deg) {
    __shared__ int hist[NBKT];
    const int tid = threadIdx.x, blk = blockIdx.x;
    for (int i = tid; i < NBKT; i += 256) hist[i] = 0;
    __syncthreads();
    const int e0 = blk * EPB, e1 = e0 + EPB;
    for (int e = e0 + tid; e < e1; e += 256) {
        int c = ei[N_EDGES + e];
        atomicAdd(&hist[c >> 8], 1);
        atomicAdd(&deg[c], ew[e]);
    }
    __syncthreads();
    for (int i = tid; i < NBKT; i += 256) mat[i * NBLKA + blk] = hist[i];
}

// ---------------- dinv = rsqrt(1 + deg) ----------------

__global__ __launch_bounds__(256) void k_dinv(const float* __restrict__ deg,
                                              float* __restrict__ dinv) {
    int i = blockIdx.x * 256 + threadIdx.x;
    if (i < N_NODES) dinv[i] = rsqrtf(1.0f + deg[i]);
}

// ---------------- S1: per-bucket exclusive scan across blocks + row totals ----------------

__global__ __launch_bounds__(256) void k_scanRows(int* __restrict__ mat,
                                                  int* __restrict__ total) {
    __shared__ int s[256];
    const int tid = threadIdx.x, bin = blockIdx.x;
    int v = mat[bin * NBLKA + tid];
    s[tid] = v;
    __syncthreads();
    for (int off = 1; off < 256; off <<= 1) {
        int t = (tid >= off) ? s[tid - off] : 0;
        __syncthreads();
        s[tid] += t;
        __syncthreads();
    }
    mat[bin * NBLKA + tid] = s[tid] - v;        // exclusive within bucket
    if (tid == 255) total[bin] = s[255];
}

// ---------------- S2: scan bucket totals -> coarse_base[NBKT+1] ----------------

__global__ __launch_bounds__(512) void k_scanTot(const int* __restrict__ total,
                                                 int* __restrict__ cbase) {
    __shared__ int s[512];
    const int tid = threadIdx.x;
    int v = (tid < NBKT) ? total[tid] : 0;
    s[tid] = v;
    __syncthreads();
    for (int off = 1; off < 512; off <<= 1) {
        int t = (tid >= off) ? s[tid - off] : 0;
        __syncthreads();
        s[tid] += t;
        __syncthreads();
    }
    if (tid <= NBKT) cbase[tid] = s[tid] - v;   // tid==NBKT: v=0 -> = E
}

// ---------------- pass B: scatter edges into coarse buckets, FULL norm applied ----------------
// tmpA.y = ew * dinv[src] * dinv[dst]  (dinv ready after k_dinv). k_norm eliminated.

__global__ __launch_bounds__(256) void k_scatterB(const int* __restrict__ ei,
                                                  const float* __restrict__ ew,
                                                  const int* __restrict__ mat,
                                                  const int* __restrict__ cbase,
                                                  const float* __restrict__ dinv,
                                                  int2* __restrict__ tmpA,
                                                  unsigned char* __restrict__ tmpD) {
    __shared__ int cur[NBKT];
    const int tid = threadIdx.x, blk = blockIdx.x;
    for (int i = tid; i < NBKT; i += 256)
        cur[i] = cbase[i] + mat[i * NBLKA + blk];
    __syncthreads();
    const int e0 = blk * EPB, e1 = e0 + EPB;
    for (int e = e0 + tid; e < e1; e += 256) {
        int r = ei[e];
        int c = ei[N_EDGES + e];
        float wn = ew[e] * dinv[r] * dinv[c];
        int slot = atomicAdd(&cur[c >> 8], 1);
        tmpA[slot] = make_int2(r, __float_as_int(wn));
        tmpD[slot] = (unsigned char)(c & 255);
    }
}

// ---------------- pass C: per-bucket fine count + scan + CSR emit (pure reorder) ----------------

__global__ __launch_bounds__(256) void k_bucketC(const int* __restrict__ cbase,
                                                 const int2* __restrict__ tmpA,
                                                 const unsigned char* __restrict__ tmpD,
                                                 int2* __restrict__ csr,
                                                 int* __restrict__ cnt,
                                                 int* __restrict__ base) {
    __shared__ int c_cnt[256];
    __shared__ int c_scan[256];
    __shared__ int c_cur[256];
    const int tid = threadIdx.x, b = blockIdx.x;
    const int s = cbase[b], e = cbase[b + 1];
    c_cnt[tid] = 0;
    __syncthreads();
    for (int j = s + tid; j < e; j += 256)
        atomicAdd(&c_cnt[tmpD[j]], 1);
    __syncthreads();
    int v = c_cnt[tid];
    c_scan[tid] = v;
    __syncthreads();
    for (int off = 1; off < 256; off <<= 1) {
        int t = (tid >= off) ? c_scan[tid - off] : 0;
        __syncthreads();
        c_scan[tid] += t;
        __syncthreads();
    }
    int excl = c_scan[tid] - v;
    c_cur[tid] = excl;
    int node = b * 256 + tid;
    if (node < N_NODES) {
        cnt[node]  = v;
        base[node] = s + excl;
    }
    __syncthreads();
    for (int j = s + tid; j < e; j += 256) {
        int d = tmpD[j];
        int slot = atomicAdd(&c_cur[d], 1);
        csr[s + slot] = tmpA[j];
    }
}

// ---------------- layer 1 GEMM via MFMA: hpre(bf16) = x @ W1 ----------------

__global__ __launch_bounds__(256) void k_gemm1(const float* __restrict__ x,
                                               const float* __restrict__ W1,
                                               unsigned short* __restrict__ hpre) {
    __shared__ __align__(16) short Wt[64 * 512];   // 65536 B
    const int tid = threadIdx.x;

    {
        const int c  = tid & 63;
        const int kb = (tid >> 6) * 128;
        const int sw = (c & 7) << 3;
        for (int kk = 0; kk < 128; kk += 8) {
            short8 v;
#pragma unroll
            for (int j = 0; j < 8; j++)
                v[j] = (short)f2bf(W1[(size_t)(kb + kk + j) * D_HID + c]);
            *(short8*)&Wt[c * 512 + ((kb + kk) ^ sw)] = v;
        }
    }
    __syncthreads();

    const int widx = blockIdx.x * 4 + (tid >> 6);
    if (widx >= N_NODES / 16) return;
    const int lane = tid & 63;
    const int q  = lane >> 4;
    const int cn = lane & 15;
    const int r0 = widx * 16;
    const int sw = (cn & 7) << 3;

    floatx4 acc[4] = {{0,0,0,0},{0,0,0,0},{0,0,0,0},{0,0,0,0}};
    const float* xp = x + (size_t)(r0 + cn) * D_FEAT + q * 8;

#pragma unroll 4
    for (int k0 = 0; k0 < D_FEAT; k0 += 32) {
        float4 xa = *(const float4*)(xp + k0);
        float4 xb = *(const float4*)(xp + k0 + 4);
        short8 a = pack_bf16x8(xa, xb);
#pragma unroll
        for (int ct = 0; ct < 4; ct++) {
            short8 b = *(const short8*)&Wt[(ct * 16 + cn) * 512 + ((k0 + q * 8) ^ sw)];
            acc[ct] = __builtin_amdgcn_mfma_f32_16x16x32_bf16(a, b, acc[ct], 0, 0, 0);
        }
    }

#pragma unroll
    for (int ct = 0; ct < 4; ct++)
#pragma unroll
        for (int i = 0; i < 4; i++)
            hpre[(size_t)(r0 + q * 4 + i) * D_HID + ct * 16 + cn] = f2bf(acc[ct][i]);
}

// ---------------- layer 1 gather + fused layer-2 linear (relu(agg+b1) @ W2) ----------------
// One wave per node; 2 edges per wave-instruction (half-wave pair scheme).
// csr streamed with NONTEMPORAL loads so the 12.8 MB hpre row table keeps L2.
// Self-loop init only in vsel=0 half. Output z bf16 rows of 64 (128B).

__global__ __launch_bounds__(256) void k_gather1(const int* __restrict__ base,
                                                 const int* __restrict__ cnt,
                                                 const int2* __restrict__ csr,
                                                 const unsigned char* __restrict__ hpreB,
                                                 const float* __restrict__ dinv,
                                                 const float* __restrict__ b1,
                                                 const float* __restrict__ W2,
                                                 unsigned short* __restrict__ z16) {
    __shared__ float hs[4][64];
    __shared__ int2  eds[4][64];
    const int lane = threadIdx.x & 63;
    const int w = threadIdx.x >> 6;
    const int n = blockIdx.x * 4 + w;
    const int s = base[n], e = s + cnt[n];
    const float dn = dinv[n];
    const int q = lane & 31;
    const int vsel = lane >> 5;
    const unsigned laneoff = (unsigned)q << 2;

    float accx[4] = {0.f, 0.f, 0.f, 0.f};
    float accy[4] = {0.f, 0.f, 0.f, 0.f};
    {
        unsigned pv = *(const unsigned*)(hpreB + (((unsigned)n) << 7) + laneoff);
        float dn2 = vsel ? 0.f : dn * dn;       // self-loop once (halves get summed)
        accx[0] = dn2 * __uint_as_float(pv << 16);
        accy[0] = dn2 * __uint_as_float(pv & 0xffff0000u);
    }

    for (int c = s; c < e; c += 64) {
        int idx = c + lane;
        int2 ed = nt_load_int2(&csr[idx < e ? idx : (e - 1)]);
        if (idx >= e) ed.y = 0;                 // zero weight for pad slots
        eds[w][lane] = ed;                      // wave-private stage (no barrier)
        int nc = e - c; if (nc > 64) nc = 64;
        for (int j = 0; j < nc; j += 16) {      // 8 edge-pairs per group
            int2 ep[8]; unsigned pv[8];
#pragma unroll
            for (int p = 0; p < 8; p++)
                ep[p] = eds[w][j + 2 * p + vsel];
#pragma unroll
            for (int p = 0; p < 8; p++)
                pv[p] = *(const unsigned*)(hpreB + (((unsigned)ep[p].x) << 7) + laneoff);
#pragma unroll
            for (int p = 0; p < 8; p++) {
                float wj = __int_as_float(ep[p].y);
                accx[p & 3] = fmaf(wj, __uint_as_float(pv[p] << 16), accx[p & 3]);
                accy[p & 3] = fmaf(wj, __uint_as_float(pv[p] & 0xffff0000u), accy[p & 3]);
            }
        }
    }

    float tx = (accx[0] + accx[1]) + (accx[2] + accx[3]);
    float ty = (accy[0] + accy[1]) + (accy[2] + accy[3]);
    tx += __shfl_xor(tx, 32, 64);
    ty += __shfl_xor(ty, 32, 64);
    if (lane < 32) {
        float h0 = tx + b1[2 * lane];
        float h1 = ty + b1[2 * lane + 1];
        hs[w][2 * lane]     = h0 > 0.f ? h0 : 0.f;
        hs[w][2 * lane + 1] = h1 > 0.f ? h1 : 0.f;
    }
    float a2 = 0.f;
    if (lane < N_CLS) {
#pragma unroll
        for (int k = 0; k < D_HID; k += 4) {
            float4 hv = *(const float4*)&hs[w][k];
            a2 += hv.x * W2[(k    ) * N_CLS + lane] + hv.y * W2[(k + 1) * N_CLS + lane]
                + hv.z * W2[(k + 2) * N_CLS + lane] + hv.w * W2[(k + 3) * N_CLS + lane];
        }
    }
    z16[(size_t)n * D_HID + lane] = (lane < N_CLS) ? f2bf(a2) : 0;
}

// ---------------- layer 2 gather + bias + log_softmax fused (pair scheme, z bf16) ----------------

__global__ __launch_bounds__(256) void k_gather2_lsm(const int* __restrict__ base,
                                                     const int* __restrict__ cnt,
                                                     const int2* __restrict__ csr,
                                                     const unsigned char* __restrict__ zB,
                                                     const float* __restrict__ dinv,
                                                     const float* __restrict__ b2,
                                                     float* __restrict__ out) {
    __shared__ int2 eds[4][64];
    const int lane = threadIdx.x & 63;
    const int w = threadIdx.x >> 6;
    const int n = blockIdx.x * 4 + w;
    const int s = base[n], e = s + cnt[n];
    const float dn = dinv[n];
    const int q = lane & 31;
    const int vsel = lane >> 5;
    const unsigned laneoff = (unsigned)q << 2;

    float accx[4] = {0.f, 0.f, 0.f, 0.f};
    float accy[4] = {0.f, 0.f, 0.f, 0.f};
    {
        unsigned pv = *(const unsigned*)(zB + (((unsigned)n) << 7) + laneoff);
        float dn2 = vsel ? 0.f : dn * dn;       // self-loop once (halves get summed)
        accx[0] = dn2 * __uint_as_float(pv << 16);
        accy[0] = dn2 * __uint_as_float(pv & 0xffff0000u);
    }

    for (int c = s; c < e; c += 64) {
        int idx = c + lane;
        int2 ed = nt_load_int2(&csr[idx < e ? idx : (e - 1)]);
        if (idx >= e) ed.y = 0;
        eds[w][lane] = ed;
        int nc = e - c; if (nc > 64) nc = 64;
        for (int j = 0; j < nc; j += 16) {
            int2 ep[8]; unsigned pv[8];
#pragma unroll
            for (int p = 0; p < 8; p++)
                ep[p] = eds[w][j + 2 * p + vsel];
#pragma unroll
            for (int p = 0; p < 8; p++)
                pv[p] = *(const unsigned*)(zB + (((unsigned)ep[p].x) << 7) + laneoff);
#pragma unroll
            for (int p = 0; p < 8; p++) {
                float wj = __int_as_float(ep[p].y);
                accx[p & 3] = fmaf(wj, __uint_as_float(pv[p] << 16), accx[p & 3]);
                accy[p & 3] = fmaf(wj, __uint_as_float(pv[p] & 0xffff0000u), accy[p & 3]);
            }
        }
    }

    float tx = (accx[0] + accx[1]) + (accx[2] + accx[3]);
    float ty = (accy[0] + accy[1]) + (accy[2] + accy[3]);
    tx += __shfl_xor(tx, 32, 64);
    ty += __shfl_xor(ty, 32, 64);

    const bool act2 = q < (N_CLS / 2);          // 20 pairs cover 40 classes
    float lg0 = 0.f, lg1 = 0.f;
    if (act2) {
        lg0 = tx + b2[2 * q];
        lg1 = ty + b2[2 * q + 1];
    }
    float m = act2 ? fmaxf(lg0, lg1) : -INFINITY;
    for (int off = 16; off; off >>= 1) m = fmaxf(m, __shfl_xor(m, off, 64));
    float ev = act2 ? (expf(lg0 - m) + expf(lg1 - m)) : 0.f;
    float sum = ev;
    for (int off = 16; off; off >>= 1) sum += __shfl_xor(sum, off, 64);
    float ls = logf(sum);
    if (lane < (N_CLS / 2)) {                   // low half writes pairs
        float2 o;
        o.x = lg0 - m - ls;
        o.y = lg1 - m - ls;
        *(float2*)(out + (size_t)n * N_CLS + 2 * lane) = o;
    }
}

// ---------------- launch ----------------

extern "C" void kernel_launch(void* const* d_in, const int* in_sizes, int n_in,
                              void* d_out, int out_size, void* d_ws, size_t ws_size,
                              hipStream_t stream) {
    const float* x  = (const float*)d_in[0];
    const int*   ei = (const int*)d_in[1];
    const float* ew = (const float*)d_in[2];
    const float* W1 = (const float*)d_in[3];
    const float* b1 = (const float*)d_in[4];
    const float* W2 = (const float*)d_in[5];
    const float* b2 = (const float*)d_in[6];
    float* out = (float*)d_out;

    // workspace layout (4B words):
    //   [0,      6.4M)   csr   int2[E]
    //   [6.4M,  12.8M)   tmpA  int2[E]  -- dead after C; hpre(bf16) [6.4M, 9.6M),
    //                                      z16(bf16)  [9.6M, 12.8M)
    //   [12.8M, 13.6M)   tmpD  uchar[E]
    //   [13.6M, ~13.71M) mat/total/cbase
    //   [16.0M, 16.4M)   cnt / base / dinv / deg (live through gathers)
    int* ws = (int*)d_ws;
    int2*          csr  = (int2*)ws;
    int2*          tmpA = (int2*)(ws + 2 * (size_t)N_EDGES);
    unsigned char* tmpD = (unsigned char*)(ws + 4 * (size_t)N_EDGES);
    int*   mat   = ws + 4 * (size_t)N_EDGES + N_EDGES / 4;
    int*   total = mat + NBKT * NBLKA;
    int*   cbase = total + NBKT;
    unsigned short* hpre = (unsigned short*)tmpA;              // [6.4M, 9.6M)
    unsigned short* z16  = hpre + (size_t)N_NODES * D_HID;     // [9.6M, 12.8M)
    int*   cnt  = ws + 16000000;
    int*   base = cnt + N_NODES;
    float* dinv = (float*)(base + N_NODES);
    float* deg  = dinv + N_NODES;

    k_zero    <<<NBKT,  256, 0, stream>>>(deg);
    k_histA   <<<NBLKA, 256, 0, stream>>>(ei, ew, mat, deg);
    k_dinv    <<<NBKT,  256, 0, stream>>>(deg, dinv);
    k_scanRows<<<NBKT,  256, 0, stream>>>(mat, total);
    k_scanTot <<<1,     512, 0, stream>>>(total, cbase);
    k_scatterB<<<NBLKA, 256, 0, stream>>>(ei, ew, mat, cbase, dinv, tmpA, tmpD);
    k_bucketC <<<NBKT,  256, 0, stream>>>(cbase, tmpA, tmpD, csr, cnt, base);
    k_gemm1   <<<(N_NODES / 16 + 3) / 4, 256, 0, stream>>>(x, W1, hpre);
    k_gather1 <<<N_NODES / 4, 256, 0, stream>>>(base, cnt, csr,
                                                (const unsigned char*)hpre, dinv, b1, W2, z16);
    k_gather2_lsm<<<N_NODES / 4, 256, 0, stream>>>(base, cnt, csr,
                                                   (const unsigned char*)z16, dinv, b2, out);
}

// Round 10
// 665.503 us; speedup vs baseline: 1.1782x; 1.1782x over previous
//
#include <hip/hip_runtime.h>
#include <math.h>

#define N_NODES 100000
#define N_EDGES 3200000
#define D_FEAT  512
#define D_HID   64
#define N_CLS   40
#define NBKT    391            /* coarse buckets = ceil(N/256), bucket = dst >> 8 */
#define NBLKA   256            /* blocks in passes A/B */
#define EPB     (N_EDGES / NBLKA)   /* 12500 edges per block */

typedef __attribute__((ext_vector_type(8))) short short8;
typedef __attribute__((ext_vector_type(4))) float floatx4;

static __device__ __forceinline__ unsigned short f2bf(float f) {
    unsigned u = __float_as_uint(f);
    unsigned r = (u + 0x7FFFu + ((u >> 16) & 1u)) >> 16;   // RNE
    return (unsigned short)r;
}
static __device__ __forceinline__ float bf2f(unsigned short h) {
    return __uint_as_float(((unsigned)h) << 16);
}
static __device__ __forceinline__ short8 pack_bf16x8(float4 a, float4 b) {
    short8 r;
    r[0] = (short)f2bf(a.x); r[1] = (short)f2bf(a.y);
    r[2] = (short)f2bf(a.z); r[3] = (short)f2bf(a.w);
    r[4] = (short)f2bf(b.x); r[5] = (short)f2bf(b.y);
    r[6] = (short)f2bf(b.z); r[7] = (short)f2bf(b.w);
    return r;
}
static __device__ __forceinline__ int2 nt_load_int2(const int2* p) {
    long long v = __builtin_nontemporal_load((const long long*)p);
    int2 r; r.x = (int)(unsigned)(v & 0xffffffffll); r.y = (int)(v >> 32);
    return r;
}

// ---------------- pass A: per-block coarse histogram (no global atomics) ----------------

__global__ __launch_bounds__(256) void k_histA(const int* __restrict__ ei,
                                               int* __restrict__ mat) {
    __shared__ int hist[NBKT];
    const int tid = threadIdx.x, blk = blockIdx.x;
    for (int i = tid; i < NBKT; i += 256) hist[i] = 0;
    __syncthreads();
    const int e0 = blk * EPB, e1 = e0 + EPB;
    for (int e = e0 + tid; e < e1; e += 256)
        atomicAdd(&hist[ei[N_EDGES + e] >> 8], 1);
    __syncthreads();
    for (int i = tid; i < NBKT; i += 256) mat[i * NBLKA + blk] = hist[i];
}

// ---------------- S1: per-bucket exclusive scan across blocks + row totals ----------------

__global__ __launch_bounds__(256) void k_scanRows(int* __restrict__ mat,
                                                  int* __restrict__ total) {
    __shared__ int s[256];
    const int tid = threadIdx.x, bin = blockIdx.x;
    int v = mat[bin * NBLKA + tid];
    s[tid] = v;
    __syncthreads();
    for (int off = 1; off < 256; off <<= 1) {
        int t = (tid >= off) ? s[tid - off] : 0;
        __syncthreads();
        s[tid] += t;
        __syncthreads();
    }
    mat[bin * NBLKA + tid] = s[tid] - v;        // exclusive within bucket
    if (tid == 255) total[bin] = s[255];
}

// ---------------- S2: scan bucket totals -> coarse_base[NBKT+1] ----------------

__global__ __launch_bounds__(512) void k_scanTot(const int* __restrict__ total,
                                                 int* __restrict__ cbase) {
    __shared__ int s[512];
    const int tid = threadIdx.x;
    int v = (tid < NBKT) ? total[tid] : 0;
    s[tid] = v;
    __syncthreads();
    for (int off = 1; off < 512; off <<= 1) {
        int t = (tid >= off) ? s[tid - off] : 0;
        __syncthreads();
        s[tid] += t;
        __syncthreads();
    }
    if (tid <= NBKT) cbase[tid] = s[tid] - v;   // tid==NBKT: v=0 -> = E
}

// ---------------- pass B: scatter edges into coarse buckets (LDS cursors only) ----------------

__global__ __launch_bounds__(256) void k_scatterB(const int* __restrict__ ei,
                                                  const float* __restrict__ ew,
                                                  const int* __restrict__ mat,
                                                  const int* __restrict__ cbase,
                                                  int2* __restrict__ tmpA,
                                                  unsigned char* __restrict__ tmpD) {
    __shared__ int cur[NBKT];
    const int tid = threadIdx.x, blk = blockIdx.x;
    for (int i = tid; i < NBKT; i += 256)
        cur[i] = cbase[i] + mat[i * NBLKA + blk];
    __syncthreads();
    const int e0 = blk * EPB, e1 = e0 + EPB;
    for (int e = e0 + tid; e < e1; e += 256) {
        int r = ei[e];
        int c = ei[N_EDGES + e];
        int slot = atomicAdd(&cur[c >> 8], 1);
        tmpA[slot] = make_int2(r, __float_as_int(ew[e]));
        tmpD[slot] = (unsigned char)(c & 255);
    }
}

// ---------------- pass C: per-bucket fine count + scan + CSR emit + dinv ----------------
// deg accumulated with per-bucket LDS float atomics (round-9's global-atomic
// version serialized: 169 µs). csr.y gets ew * dinv[dst]; src side in k_norm.

__global__ __launch_bounds__(256) void k_bucketC(const int* __restrict__ cbase,
                                                 const int2* __restrict__ tmpA,
                                                 const unsigned char* __restrict__ tmpD,
                                                 int2* __restrict__ csr,
                                                 int* __restrict__ cnt,
                                                 int* __restrict__ base,
                                                 float* __restrict__ dinv) {
    __shared__ int   c_cnt[256];
    __shared__ float c_deg[256];
    __shared__ int   c_scan[256];
    __shared__ int   c_cur[256];
    __shared__ float c_dnv[256];
    const int tid = threadIdx.x, b = blockIdx.x;
    const int s = cbase[b], e = cbase[b + 1];
    c_cnt[tid] = 0;
    c_deg[tid] = 0.f;
    __syncthreads();
    for (int j = s + tid; j < e; j += 256) {
        int d = tmpD[j];
        atomicAdd(&c_cnt[d], 1);
        atomicAdd(&c_deg[d], __int_as_float(tmpA[j].y));
    }
    __syncthreads();
    int v = c_cnt[tid];
    c_scan[tid] = v;
    __syncthreads();
    for (int off = 1; off < 256; off <<= 1) {
        int t = (tid >= off) ? c_scan[tid - off] : 0;
        __syncthreads();
        c_scan[tid] += t;
        __syncthreads();
    }
    int excl = c_scan[tid] - v;
    c_cur[tid] = excl;
    float dv = rsqrtf(1.0f + c_deg[tid]);        // self-loop weight 1
    c_dnv[tid] = dv;
    int node = b * 256 + tid;
    if (node < N_NODES) {
        cnt[node]  = v;
        base[node] = s + excl;
        dinv[node] = dv;
    }
    __syncthreads();
    for (int j = s + tid; j < e; j += 256) {
        int d = tmpD[j];
        int2 p = tmpA[j];
        int slot = atomicAdd(&c_cur[d], 1);
        csr[s + slot] = make_int2(p.x, __float_as_int(__int_as_float(p.y) * c_dnv[d]));
    }
}

// ---------------- norm pass: fold dinv[src] into csr weights (edge-parallel) ----------------

__global__ __launch_bounds__(256) void k_norm(int2* __restrict__ csr,
                                              const float* __restrict__ dinv) {
    int i = blockIdx.x * 256 + threadIdx.x;
    int2 p = csr[i];
    p.y = __float_as_int(__int_as_float(p.y) * dinv[p.x]);
    csr[i] = p;
}

// ---------------- layer 1 GEMM via MFMA: hpre(bf16) = x @ W1 ----------------

__global__ __launch_bounds__(256) void k_gemm1(const float* __restrict__ x,
                                               const float* __restrict__ W1,
                                               unsigned short* __restrict__ hpre) {
    __shared__ __align__(16) short Wt[64 * 512];   // 65536 B
    const int tid = threadIdx.x;

    {
        const int c  = tid & 63;
        const int kb = (tid >> 6) * 128;
        const int sw = (c & 7) << 3;
        for (int kk = 0; kk < 128; kk += 8) {
            short8 v;
#pragma unroll
            for (int j = 0; j < 8; j++)
                v[j] = (short)f2bf(W1[(size_t)(kb + kk + j) * D_HID + c]);
            *(short8*)&Wt[c * 512 + ((kb + kk) ^ sw)] = v;
        }
    }
    __syncthreads();

    const int widx = blockIdx.x * 4 + (tid >> 6);
    if (widx >= N_NODES / 16) return;
    const int lane = tid & 63;
    const int q  = lane >> 4;
    const int cn = lane & 15;
    const int r0 = widx * 16;
    const int sw = (cn & 7) << 3;

    floatx4 acc[4] = {{0,0,0,0},{0,0,0,0},{0,0,0,0},{0,0,0,0}};
    const float* xp = x + (size_t)(r0 + cn) * D_FEAT + q * 8;

#pragma unroll 4
    for (int k0 = 0; k0 < D_FEAT; k0 += 32) {
        float4 xa = *(const float4*)(xp + k0);
        float4 xb = *(const float4*)(xp + k0 + 4);
        short8 a = pack_bf16x8(xa, xb);
#pragma unroll
        for (int ct = 0; ct < 4; ct++) {
            short8 b = *(const short8*)&Wt[(ct * 16 + cn) * 512 + ((k0 + q * 8) ^ sw)];
            acc[ct] = __builtin_amdgcn_mfma_f32_16x16x32_bf16(a, b, acc[ct], 0, 0, 0);
        }
    }

#pragma unroll
    for (int ct = 0; ct < 4; ct++)
#pragma unroll
        for (int i = 0; i < 4; i++)
            hpre[(size_t)(r0 + q * 4 + i) * D_HID + ct * 16 + cn] = f2bf(acc[ct][i]);
}

// ---------------- layer 1 gather + fused layer-2 linear (relu(agg+b1) @ W2) ----------------
// One wave per node; 2 edges per wave-instruction (half-wave pair scheme).
// csr streamed with NONTEMPORAL loads so the 12.8 MB hpre row table keeps L2.
// Self-loop init only in vsel=0 half. Output z bf16 rows of 64 (128B).

__global__ __launch_bounds__(256) void k_gather1(const int* __restrict__ base,
                                                 const int* __restrict__ cnt,
                                                 const int2* __restrict__ csr,
                                                 const unsigned char* __restrict__ hpreB,
                                                 const float* __restrict__ dinv,
                                                 const float* __restrict__ b1,
                                                 const float* __restrict__ W2,
                                                 unsigned short* __restrict__ z16) {
    __shared__ float hs[4][64];
    __shared__ int2  eds[4][64];
    const int lane = threadIdx.x & 63;
    const int w = threadIdx.x >> 6;
    const int n = blockIdx.x * 4 + w;
    const int s = base[n], e = s + cnt[n];
    const float dn = dinv[n];
    const int q = lane & 31;
    const int vsel = lane >> 5;
    const unsigned laneoff = (unsigned)q << 2;

    float accx[4] = {0.f, 0.f, 0.f, 0.f};
    float accy[4] = {0.f, 0.f, 0.f, 0.f};
    {
        unsigned pv = *(const unsigned*)(hpreB + (((unsigned)n) << 7) + laneoff);
        float dn2 = vsel ? 0.f : dn * dn;       // self-loop once (halves get summed)
        accx[0] = dn2 * __uint_as_float(pv << 16);
        accy[0] = dn2 * __uint_as_float(pv & 0xffff0000u);
    }

    for (int c = s; c < e; c += 64) {
        int idx = c + lane;
        int2 ed = nt_load_int2(&csr[idx < e ? idx : (e - 1)]);
        if (idx >= e) ed.y = 0;                 // zero weight for pad slots
        eds[w][lane] = ed;                      // wave-private stage (no barrier)
        int nc = e - c; if (nc > 64) nc = 64;
        for (int j = 0; j < nc; j += 16) {      // 8 edge-pairs per group
            int2 ep[8]; unsigned pv[8];
#pragma unroll
            for (int p = 0; p < 8; p++)
                ep[p] = eds[w][j + 2 * p + vsel];
#pragma unroll
            for (int p = 0; p < 8; p++)
                pv[p] = *(const unsigned*)(hpreB + (((unsigned)ep[p].x) << 7) + laneoff);
#pragma unroll
            for (int p = 0; p < 8; p++) {
                float wj = __int_as_float(ep[p].y);
                accx[p & 3] = fmaf(wj, __uint_as_float(pv[p] << 16), accx[p & 3]);
                accy[p & 3] = fmaf(wj, __uint_as_float(pv[p] & 0xffff0000u), accy[p & 3]);
            }
        }
    }

    float tx = (accx[0] + accx[1]) + (accx[2] + accx[3]);
    float ty = (accy[0] + accy[1]) + (accy[2] + accy[3]);
    tx += __shfl_xor(tx, 32, 64);
    ty += __shfl_xor(ty, 32, 64);
    if (lane < 32) {
        float h0 = tx + b1[2 * lane];
        float h1 = ty + b1[2 * lane + 1];
        hs[w][2 * lane]     = h0 > 0.f ? h0 : 0.f;
        hs[w][2 * lane + 1] = h1 > 0.f ? h1 : 0.f;
    }
    float a2 = 0.f;
    if (lane < N_CLS) {
#pragma unroll
        for (int k = 0; k < D_HID; k += 4) {
            float4 hv = *(const float4*)&hs[w][k];
            a2 += hv.x * W2[(k    ) * N_CLS + lane] + hv.y * W2[(k + 1) * N_CLS + lane]
                + hv.z * W2[(k + 2) * N_CLS + lane] + hv.w * W2[(k + 3) * N_CLS + lane];
        }
    }
    z16[(size_t)n * D_HID + lane] = (lane < N_CLS) ? f2bf(a2) : 0;
}

// ---------------- layer 2 gather + bias + log_softmax fused (pair scheme, z bf16) ----------------

__global__ __launch_bounds__(256) void k_gather2_lsm(const int* __restrict__ base,
                                                     const int* __restrict__ cnt,
                                                     const int2* __restrict__ csr,
                                                     const unsigned char* __restrict__ zB,
                                                     const float* __restrict__ dinv,
                                                     const float* __restrict__ b2,
                                                     float* __restrict__ out) {
    __shared__ int2 eds[4][64];
    const int lane = threadIdx.x & 63;
    const int w = threadIdx.x >> 6;
    const int n = blockIdx.x * 4 + w;
    const int s = base[n], e = s + cnt[n];
    const float dn = dinv[n];
    const int q = lane & 31;
    const int vsel = lane >> 5;
    const unsigned laneoff = (unsigned)q << 2;

    float accx[4] = {0.f, 0.f, 0.f, 0.f};
    float accy[4] = {0.f, 0.f, 0.f, 0.f};
    {
        unsigned pv = *(const unsigned*)(zB + (((unsigned)n) << 7) + laneoff);
        float dn2 = vsel ? 0.f : dn * dn;       // self-loop once (halves get summed)
        accx[0] = dn2 * __uint_as_float(pv << 16);
        accy[0] = dn2 * __uint_as_float(pv & 0xffff0000u);
    }

    for (int c = s; c < e; c += 64) {
        int idx = c + lane;
        int2 ed = nt_load_int2(&csr[idx < e ? idx : (e - 1)]);
        if (idx >= e) ed.y = 0;
        eds[w][lane] = ed;
        int nc = e - c; if (nc > 64) nc = 64;
        for (int j = 0; j < nc; j += 16) {
            int2 ep[8]; unsigned pv[8];
#pragma unroll
            for (int p = 0; p < 8; p++)
                ep[p] = eds[w][j + 2 * p + vsel];
#pragma unroll
            for (int p = 0; p < 8; p++)
                pv[p] = *(const unsigned*)(zB + (((unsigned)ep[p].x) << 7) + laneoff);
#pragma unroll
            for (int p = 0; p < 8; p++) {
                float wj = __int_as_float(ep[p].y);
                accx[p & 3] = fmaf(wj, __uint_as_float(pv[p] << 16), accx[p & 3]);
                accy[p & 3] = fmaf(wj, __uint_as_float(pv[p] & 0xffff0000u), accy[p & 3]);
            }
        }
    }

    float tx = (accx[0] + accx[1]) + (accx[2] + accx[3]);
    float ty = (accy[0] + accy[1]) + (accy[2] + accy[3]);
    tx += __shfl_xor(tx, 32, 64);
    ty += __shfl_xor(ty, 32, 64);

    const bool act2 = q < (N_CLS / 2);          // 20 pairs cover 40 classes
    float lg0 = 0.f, lg1 = 0.f;
    if (act2) {
        lg0 = tx + b2[2 * q];
        lg1 = ty + b2[2 * q + 1];
    }
    float m = act2 ? fmaxf(lg0, lg1) : -INFINITY;
    for (int off = 16; off; off >>= 1) m = fmaxf(m, __shfl_xor(m, off, 64));
    float ev = act2 ? (expf(lg0 - m) + expf(lg1 - m)) : 0.f;
    float sum = ev;
    for (int off = 16; off; off >>= 1) sum += __shfl_xor(sum, off, 64);
    float ls = logf(sum);
    if (lane < (N_CLS / 2)) {                   // low half writes pairs
        float2 o;
        o.x = lg0 - m - ls;
        o.y = lg1 - m - ls;
        *(float2*)(out + (size_t)n * N_CLS + 2 * lane) = o;
    }
}

// ---------------- launch ----------------

extern "C" void kernel_launch(void* const* d_in, const int* in_sizes, int n_in,
                              void* d_out, int out_size, void* d_ws, size_t ws_size,
                              hipStream_t stream) {
    const float* x  = (const float*)d_in[0];
    const int*   ei = (const int*)d_in[1];
    const float* ew = (const float*)d_in[2];
    const float* W1 = (const float*)d_in[3];
    const float* b1 = (const float*)d_in[4];
    const float* W2 = (const float*)d_in[5];
    const float* b2 = (const float*)d_in[6];
    float* out = (float*)d_out;

    // workspace layout (4B words):
    //   [0,      6.4M)   csr   int2[E]
    //   [6.4M,  12.8M)   tmpA  int2[E]  -- dead after C; hpre(bf16) [6.4M, 9.6M),
    //                                      z16(bf16)  [9.6M, 12.8M)
    //   [12.8M, 13.6M)   tmpD  uchar[E]
    //   [13.6M, ~13.71M) mat/total/cbase
    //   [16.0M, 16.3M)   cnt / base / dinv (live through gathers)
    int* ws = (int*)d_ws;
    int2*          csr  = (int2*)ws;
    int2*          tmpA = (int2*)(ws + 2 * (size_t)N_EDGES);
    unsigned char* tmpD = (unsigned char*)(ws + 4 * (size_t)N_EDGES);
    int*   mat   = ws + 4 * (size_t)N_EDGES + N_EDGES / 4;
    int*   total = mat + NBKT * NBLKA;
    int*   cbase = total + NBKT;
    unsigned short* hpre = (unsigned short*)tmpA;              // [6.4M, 9.6M)
    unsigned short* z16  = hpre + (size_t)N_NODES * D_HID;     // [9.6M, 12.8M)
    int*   cnt  = ws + 16000000;
    int*   base = cnt + N_NODES;
    float* dinv = (float*)(base + N_NODES);

    k_histA   <<<NBLKA, 256, 0, stream>>>(ei, mat);
    k_scanRows<<<NBKT,  256, 0, stream>>>(mat, total);
    k_scanTot <<<1,     512, 0, stream>>>(total, cbase);
    k_scatterB<<<NBLKA, 256, 0, stream>>>(ei, ew, mat, cbase, tmpA, tmpD);
    k_bucketC <<<NBKT,  256, 0, stream>>>(cbase, tmpA, tmpD, csr, cnt, base, dinv);
    k_norm    <<<N_EDGES / 256, 256, 0, stream>>>(csr, dinv);
    k_gemm1   <<<(N_NODES / 16 + 3) / 4, 256, 0, stream>>>(x, W1, hpre);
    k_gather1 <<<N_NODES / 4, 256, 0, stream>>>(base, cnt, csr,
                                                (const unsigned char*)hpre, dinv, b1, W2, z16);
    k_gather2_lsm<<<N_NODES / 4, 256, 0, stream>>>(base, cnt, csr,
                                                   (const unsigned char*)z16, dinv, b2, out);
}